// Round 1
// baseline (59.834 us; speedup 1.0000x reference)
//
#include <hip/hip_runtime.h>
#include <math.h>

#define B 8
#define S 1024
#define L 2048
#define D 1024

// ---- workspace layout (floats) ----
// [0,      16384)  enc_eff[b][l]   masked enc scores (+b_ptr)
// [16384,  32768)  pw[b][l]        softmax weights
// [32768, 557056)  part[b][64][d]  partial context sums
// [557056,565248)  ctx[b][d]
// [565248,565256)  cw[b]           ctx[b]·w_pgen[D:2D]
#define WS_ENC 0
#define WS_PW 16384
#define WS_PART 32768
#define WS_CTX 557056
#define WS_CW 565248

// K1: enc_eff[b,l] = mask ? dot(enc[b,l,:], w_ptr[D:]) + b_ptr : -1e9
__global__ __launch_bounds__(256) void k_enc_score(const float* __restrict__ enc,
                                                   const int* __restrict__ mask,
                                                   const float* __restrict__ w_ptr,
                                                   const float* __restrict__ b_ptr,
                                                   float* __restrict__ ws_enc) {
    int wave = threadIdx.x >> 6;
    int lane = threadIdx.x & 63;
    int r = blockIdx.x * 4 + wave;  // [0, B*L)
    const float4* row = (const float4*)(enc + (size_t)r * D);
    const float4* w = (const float4*)(w_ptr + D);
    float acc = 0.f;
#pragma unroll
    for (int k = lane, it = 0; it < 4; k += 64, ++it) {
        float4 a = row[k];
        float4 b4 = w[k];
        acc += a.x * b4.x + a.y * b4.y + a.z * b4.z + a.w * b4.w;
    }
#pragma unroll
    for (int off = 32; off > 0; off >>= 1) acc += __shfl_down(acc, off, 64);
    if (lane == 0) {
        ws_enc[r] = (mask[r] == 0) ? -1e9f : (acc + b_ptr[0]);
    }
}

// K2: pw[b,:] = softmax(enc_eff[b,:]) over L=2048. One block per b.
__global__ __launch_bounds__(256) void k_softmax(const float* __restrict__ ws_enc,
                                                 float* __restrict__ ws_pw) {
    int b = blockIdx.x;
    int tid = threadIdx.x;
    int wave = tid >> 6, lane = tid & 63;
    const float* x = ws_enc + b * L;
    float v[8];
    float mx = -INFINITY;
#pragma unroll
    for (int j = 0; j < 8; j++) {
        v[j] = x[tid + j * 256];
        mx = fmaxf(mx, v[j]);
    }
#pragma unroll
    for (int off = 32; off > 0; off >>= 1) mx = fmaxf(mx, __shfl_xor(mx, off, 64));
    __shared__ float sm[4];
    if (lane == 0) sm[wave] = mx;
    __syncthreads();
    mx = fmaxf(fmaxf(sm[0], sm[1]), fmaxf(sm[2], sm[3]));

    float e[8];
    float sum = 0.f;
#pragma unroll
    for (int j = 0; j < 8; j++) {
        e[j] = expf(v[j] - mx);
        sum += e[j];
    }
#pragma unroll
    for (int off = 32; off > 0; off >>= 1) sum += __shfl_xor(sum, off, 64);
    __shared__ float ss[4];
    if (lane == 0) ss[wave] = sum;
    __syncthreads();
    sum = ss[0] + ss[1] + ss[2] + ss[3];
    float inv = 1.0f / sum;
#pragma unroll
    for (int j = 0; j < 8; j++) ws_pw[b * L + tid + j * 256] = e[j] * inv;
}

// K3a: part[b,ch,d] = sum_{l in chunk ch (32 l's)} pw[b,l] * enc[b,l,d]
__global__ __launch_bounds__(256) void k_ctx_partial(const float* __restrict__ enc,
                                                     const float* __restrict__ ws_pw,
                                                     float* __restrict__ part) {
    int bid = blockIdx.x;  // 2048 = B(8) * dt(4) * ch(64)
    int ch = bid & 63;
    int dt = (bid >> 6) & 3;
    int b = bid >> 8;
    int d = dt * 256 + threadIdx.x;
    __shared__ float w[32];
    if (threadIdx.x < 32) w[threadIdx.x] = ws_pw[b * L + ch * 32 + threadIdx.x];
    __syncthreads();
    const float* base = enc + ((size_t)(b * L + ch * 32)) * D + d;
    float acc = 0.f;
#pragma unroll 8
    for (int j = 0; j < 32; j++) acc += w[j] * base[(size_t)j * D];
    part[((b * 64 + ch) * D) + d] = acc;
}

// K3b: ctx[b,d] = sum_ch part[b,ch,d]
__global__ __launch_bounds__(256) void k_ctx_reduce(const float* __restrict__ part,
                                                    float* __restrict__ ctx) {
    int idx = blockIdx.x * 256 + threadIdx.x;  // [0, B*D)
    int b = idx >> 10;                         // D = 1024
    int d = idx & 1023;
    float acc = 0.f;
#pragma unroll 8
    for (int ch = 0; ch < 64; ch++) acc += part[((b * 64 + ch) * D) + d];
    ctx[idx] = acc;
}

// K4a: cw[b] = dot(ctx[b,:], w_pgen[D:2D])
__global__ __launch_bounds__(256) void k_cw(const float* __restrict__ ctx,
                                            const float* __restrict__ w_pgen,
                                            float* __restrict__ cw) {
    int b = blockIdx.x;
    int tid = threadIdx.x;
    int wave = tid >> 6, lane = tid & 63;
    float acc = 0.f;
    for (int k = tid; k < D; k += 256) acc += ctx[b * D + k] * w_pgen[D + k];
#pragma unroll
    for (int off = 32; off > 0; off >>= 1) acc += __shfl_down(acc, off, 64);
    __shared__ float sm[4];
    if (lane == 0) sm[wave] = acc;
    __syncthreads();
    if (tid == 0) cw[b] = sm[0] + sm[1] + sm[2] + sm[3];
}

// K4: p_gen[b,s] = sigmoid(dec[b,s,:]·(w1+w3) + cw[b] + b_pgen)
__global__ __launch_bounds__(256) void k_pgen(const float* __restrict__ dec,
                                              const float* __restrict__ w_pgen,
                                              const float* __restrict__ b_pgen,
                                              const float* __restrict__ cw,
                                              float* __restrict__ out_pgen) {
    int wave = threadIdx.x >> 6;
    int lane = threadIdx.x & 63;
    int r = blockIdx.x * 4 + wave;  // [0, B*S)
    int b = r >> 10;                // S = 1024
    const float4* row = (const float4*)(dec + (size_t)r * D);
    const float4* w1 = (const float4*)(w_pgen);
    const float4* w3 = (const float4*)(w_pgen + 2 * D);
    float acc = 0.f;
#pragma unroll
    for (int k = lane, it = 0; it < 4; k += 64, ++it) {
        float4 a = row[k];
        float4 u = w1[k];
        float4 t = w3[k];
        acc += a.x * (u.x + t.x) + a.y * (u.y + t.y) + a.z * (u.z + t.z) +
               a.w * (u.w + t.w);
    }
#pragma unroll
    for (int off = 32; off > 0; off >>= 1) acc += __shfl_down(acc, off, 64);
    if (lane == 0) {
        float logit = acc + cw[b] + b_pgen[0];
        out_pgen[r] = 1.0f / (1.0f + expf(-logit));
    }
}

// K5: broadcast pw -> out0 [B,S,L], ctx -> out2 [B,S,D] (float4 streaming stores)
__global__ __launch_bounds__(256) void k_broadcast(const float* __restrict__ ws_pw,
                                                   const float* __restrict__ ctx,
                                                   float* __restrict__ out) {
    const long long N0 = (long long)B * S * (L / 4);  // 4194304
    const long long N2 = (long long)B * S * (D / 4);  // 2097152
    float4* out0 = (float4*)out;
    float4* out2 = (float4*)(out + (size_t)B * S * L + (size_t)B * S);
    const float4* pw4 = (const float4*)ws_pw;
    const float4* ctx4 = (const float4*)ctx;
    long long stride = (long long)gridDim.x * blockDim.x;
    for (long long i = (long long)blockIdx.x * 256 + threadIdx.x; i < N0 + N2;
         i += stride) {
        if (i < N0) {
            int l4 = (int)(i & 511);  // L/4 = 512
            int b = (int)(i >> 19);   // 512*1024
            out0[i] = pw4[b * 512 + l4];
        } else {
            long long j = i - N0;
            int d4 = (int)(j & 255);  // D/4 = 256
            int b = (int)(j >> 18);   // 256*1024
            out2[j] = ctx4[b * 256 + d4];
        }
    }
}

extern "C" void kernel_launch(void* const* d_in, const int* in_sizes, int n_in,
                              void* d_out, int out_size, void* d_ws, size_t ws_size,
                              hipStream_t stream) {
    const float* dec = (const float*)d_in[0];
    const float* enc = (const float*)d_in[1];
    const int* mask = (const int*)d_in[2];
    // d_in[3] = input_ids: unused by the reference computation
    const float* w_ptr = (const float*)d_in[4];
    const float* b_ptr = (const float*)d_in[5];
    const float* w_pgen = (const float*)d_in[6];
    const float* b_pgen = (const float*)d_in[7];
    float* out = (float*)d_out;
    float* ws = (float*)d_ws;

    float* ws_enc = ws + WS_ENC;
    float* ws_pw = ws + WS_PW;
    float* ws_part = ws + WS_PART;
    float* ws_ctx = ws + WS_CTX;
    float* ws_cw = ws + WS_CW;

    k_enc_score<<<(B * L) / 4, 256, 0, stream>>>(enc, mask, w_ptr, b_ptr, ws_enc);
    k_softmax<<<B, 256, 0, stream>>>(ws_enc, ws_pw);
    k_ctx_partial<<<B * 4 * 64, 256, 0, stream>>>(enc, ws_pw, ws_part);
    k_ctx_reduce<<<(B * D) / 256, 256, 0, stream>>>(ws_part, ws_ctx);
    k_cw<<<B, 256, 0, stream>>>(ws_ctx, w_pgen, ws_cw);
    k_pgen<<<(B * S) / 4, 256, 0, stream>>>(dec, w_pgen, b_pgen, ws_cw,
                                            out + (size_t)B * S * L);
    k_broadcast<<<2048, 256, 0, stream>>>(ws_pw, ws_ctx, out);
}

// Round 2
// 58.106 us; speedup vs baseline: 1.0297x; 1.0297x over previous
//
#include <hip/hip_runtime.h>
#include <math.h>

#define B 8
#define S 1024
#define L 2048
#define D 1024

// ---- workspace layout (floats) ----
#define WS_ENC 0
#define WS_PW 16384
#define WS_PART 32768
#define WS_CTX 557056
#define WS_CW 565248

// K1: enc_eff[b,l] = mask ? dot(enc[b,l,:], w_ptr[D:]) + b_ptr : -1e9
// Masked rows skip the 4KB row read entirely (wave-uniform branch).
__global__ __launch_bounds__(256) void k_enc_score(const float* __restrict__ enc,
                                                   const int* __restrict__ mask,
                                                   const float* __restrict__ w_ptr,
                                                   const float* __restrict__ b_ptr,
                                                   float* __restrict__ ws_enc) {
    int wave = threadIdx.x >> 6;
    int lane = threadIdx.x & 63;
    int r = blockIdx.x * 4 + wave;  // [0, B*L)
    if (mask[r] == 0) {
        if (lane == 0) ws_enc[r] = -1e9f;
        return;
    }
    const float4* row = (const float4*)(enc + (size_t)r * D);
    const float4* w = (const float4*)(w_ptr + D);
    float acc = 0.f;
#pragma unroll
    for (int k = lane, it = 0; it < 4; k += 64, ++it) {
        float4 a = row[k];
        float4 b4 = w[k];
        acc += a.x * b4.x + a.y * b4.y + a.z * b4.z + a.w * b4.w;
    }
#pragma unroll
    for (int off = 32; off > 0; off >>= 1) acc += __shfl_down(acc, off, 64);
    if (lane == 0) ws_enc[r] = acc + b_ptr[0];
}

// K2: pw[b,:] = softmax(enc_eff[b,:]) over L=2048. One block per b.
__global__ __launch_bounds__(256) void k_softmax(const float* __restrict__ ws_enc,
                                                 float* __restrict__ ws_pw) {
    int b = blockIdx.x;
    int tid = threadIdx.x;
    int wave = tid >> 6, lane = tid & 63;
    const float* x = ws_enc + b * L;
    float v[8];
    float mx = -INFINITY;
#pragma unroll
    for (int j = 0; j < 8; j++) {
        v[j] = x[tid + j * 256];
        mx = fmaxf(mx, v[j]);
    }
#pragma unroll
    for (int off = 32; off > 0; off >>= 1) mx = fmaxf(mx, __shfl_xor(mx, off, 64));
    __shared__ float sm[4];
    if (lane == 0) sm[wave] = mx;
    __syncthreads();
    mx = fmaxf(fmaxf(sm[0], sm[1]), fmaxf(sm[2], sm[3]));

    float e[8];
    float sum = 0.f;
#pragma unroll
    for (int j = 0; j < 8; j++) {
        e[j] = expf(v[j] - mx);
        sum += e[j];
    }
#pragma unroll
    for (int off = 32; off > 0; off >>= 1) sum += __shfl_xor(sum, off, 64);
    __shared__ float ss[4];
    if (lane == 0) ss[wave] = sum;
    __syncthreads();
    sum = ss[0] + ss[1] + ss[2] + ss[3];
    float inv = 1.0f / sum;
#pragma unroll
    for (int j = 0; j < 8; j++) ws_pw[b * L + tid + j * 256] = e[j] * inv;
}

// K3: part[b,ch,d] = sum over nonzero-weight l in chunk ch of pw[b,l]*enc[b,l,d].
// Ballot-compact the ~50% nonzero rows; zero-weight rows contribute exactly 0.
__global__ __launch_bounds__(256) void k_ctx_partial(const float* __restrict__ enc,
                                                     const float* __restrict__ ws_pw,
                                                     float* __restrict__ part) {
    int bid = blockIdx.x;  // 2048 = B(8) * dt(4) * ch(64)
    int ch = bid & 63;
    int dt = (bid >> 6) & 3;
    int b = bid >> 8;
    int d = dt * 256 + threadIdx.x;
    int tid = threadIdx.x;
    __shared__ float sw[32];
    __shared__ int jidx[32];
    __shared__ int sm_cnt;
    if (tid < 64) {
        float wj = (tid < 32) ? ws_pw[b * L + ch * 32 + tid] : 0.f;
        unsigned long long bal = __ballot(wj != 0.f);
        if (wj != 0.f) {
            int pos = __popcll(bal & ((1ull << tid) - 1ull));
            sw[pos] = wj;
            jidx[pos] = tid;
        }
        if (tid == 0) sm_cnt = (int)__popcll(bal);
    }
    __syncthreads();
    int m = sm_cnt;
    const float* base = enc + ((size_t)(b * L + ch * 32)) * D + d;
    float acc = 0.f;
    int k = 0;
    for (; k + 4 <= m; k += 4) {
        float a0 = base[(size_t)jidx[k + 0] * D];
        float a1 = base[(size_t)jidx[k + 1] * D];
        float a2 = base[(size_t)jidx[k + 2] * D];
        float a3 = base[(size_t)jidx[k + 3] * D];
        acc += sw[k + 0] * a0;
        acc += sw[k + 1] * a1;
        acc += sw[k + 2] * a2;
        acc += sw[k + 3] * a3;
    }
    for (; k < m; ++k) acc += sw[k] * base[(size_t)jidx[k] * D];
    part[((b * 64 + ch) * D) + d] = acc;
}

// K4: ctx[b,d] = sum_ch part[b,ch,d];  cw[b] = dot(ctx[b,:], w_pgen[D:2D])
__global__ __launch_bounds__(256) void k_reduce_cw(const float* __restrict__ part,
                                                   const float* __restrict__ w_pgen,
                                                   float* __restrict__ ctx,
                                                   float* __restrict__ cw) {
    int b = blockIdx.x;
    int tid = threadIdx.x;
    float cacc = 0.f;
    for (int d = tid; d < D; d += 256) {
        float a = 0.f;
#pragma unroll 8
        for (int ch = 0; ch < 64; ch++) a += part[((b * 64 + ch) * D) + d];
        ctx[b * D + d] = a;
        cacc += a * w_pgen[D + d];
    }
#pragma unroll
    for (int off = 32; off > 0; off >>= 1) cacc += __shfl_down(cacc, off, 64);
    __shared__ float sm[4];
    if ((tid & 63) == 0) sm[tid >> 6] = cacc;
    __syncthreads();
    if (tid == 0) cw[b] = sm[0] + sm[1] + sm[2] + sm[3];
}

// K5: fused. Blocks [0,2048): broadcast pw->out0, ctx->out2 (float4 stores).
//            Blocks [2048,4096): p_gen[b,s] = sigmoid(dec·(w1+w3) + cw[b] + b_pgen)
__global__ __launch_bounds__(256) void k_pgen_bcast(const float* __restrict__ dec,
                                                    const float* __restrict__ w_pgen,
                                                    const float* __restrict__ b_pgen,
                                                    const float* __restrict__ cw,
                                                    const float* __restrict__ ws_pw,
                                                    const float* __restrict__ ctx,
                                                    float* __restrict__ out) {
    const int BCAST_BLOCKS = 2048;
    if (blockIdx.x < BCAST_BLOCKS) {
        const long long N0 = (long long)B * S * (L / 4);  // 4194304
        const long long N2 = (long long)B * S * (D / 4);  // 2097152
        float4* out0 = (float4*)out;
        float4* out2 = (float4*)(out + (size_t)B * S * L + (size_t)B * S);
        const float4* pw4 = (const float4*)ws_pw;
        const float4* ctx4 = (const float4*)ctx;
        const long long stride = (long long)BCAST_BLOCKS * 256;
        for (long long i = (long long)blockIdx.x * 256 + threadIdx.x; i < N0 + N2;
             i += stride) {
            if (i < N0) {
                int l4 = (int)(i & 511);  // L/4 = 512
                int b = (int)(i >> 19);   // 512*1024
                out0[i] = pw4[b * 512 + l4];
            } else {
                long long j = i - N0;
                int d4 = (int)(j & 255);  // D/4 = 256
                int b = (int)(j >> 18);   // 256*1024
                out2[j] = ctx4[b * 256 + d4];
            }
        }
    } else {
        int wave = threadIdx.x >> 6;
        int lane = threadIdx.x & 63;
        int r = (blockIdx.x - BCAST_BLOCKS) * 4 + wave;  // [0, B*S)
        int b = r >> 10;                                 // S = 1024
        const float4* row = (const float4*)(dec + (size_t)r * D);
        const float4* w1 = (const float4*)(w_pgen);
        const float4* w3 = (const float4*)(w_pgen + 2 * D);
        float acc = 0.f;
#pragma unroll
        for (int k = lane, it = 0; it < 4; k += 64, ++it) {
            float4 a = row[k];
            float4 u = w1[k];
            float4 t = w3[k];
            acc += a.x * (u.x + t.x) + a.y * (u.y + t.y) + a.z * (u.z + t.z) +
                   a.w * (u.w + t.w);
        }
#pragma unroll
        for (int off = 32; off > 0; off >>= 1) acc += __shfl_down(acc, off, 64);
        if (lane == 0) {
            float logit = acc + cw[b] + b_pgen[0];
            out[(size_t)B * S * L + r] = 1.0f / (1.0f + expf(-logit));
        }
    }
}

extern "C" void kernel_launch(void* const* d_in, const int* in_sizes, int n_in,
                              void* d_out, int out_size, void* d_ws, size_t ws_size,
                              hipStream_t stream) {
    const float* dec = (const float*)d_in[0];
    const float* enc = (const float*)d_in[1];
    const int* mask = (const int*)d_in[2];
    const float* w_ptr = (const float*)d_in[4];
    const float* b_ptr = (const float*)d_in[5];
    const float* w_pgen = (const float*)d_in[6];
    const float* b_pgen = (const float*)d_in[7];
    float* out = (float*)d_out;
    float* ws = (float*)d_ws;

    float* ws_enc = ws + WS_ENC;
    float* ws_pw = ws + WS_PW;
    float* ws_part = ws + WS_PART;
    float* ws_ctx = ws + WS_CTX;
    float* ws_cw = ws + WS_CW;

    k_enc_score<<<(B * L) / 4, 256, 0, stream>>>(enc, mask, w_ptr, b_ptr, ws_enc);
    k_softmax<<<B, 256, 0, stream>>>(ws_enc, ws_pw);
    k_ctx_partial<<<B * 4 * 64, 256, 0, stream>>>(enc, ws_pw, ws_part);
    k_reduce_cw<<<B, 256, 0, stream>>>(ws_part, w_pgen, ws_ctx, ws_cw);
    k_pgen_bcast<<<4096, 256, 0, stream>>>(dec, w_pgen, b_pgen, ws_cw, ws_pw,
                                           ws_ctx, out);
}

// Round 3
// 50.532 us; speedup vs baseline: 1.1841x; 1.1499x over previous
//
#include <hip/hip_runtime.h>
#include <math.h>

#define B 8
#define S 1024
#define L 2048
#define D 1024

// ---- workspace layout (floats) ----
#define WS_E 0                      // [B*L]    unnormalized exp scores (0 if masked)
#define WS_DL (B * L)               // [B*S]    dec·(w1+w3) + b_pgen
#define WS_PART (WS_DL + B * S)     // [B*64*D] partial unnormalized ctx
#define WS_PW (WS_PART + B * 64 * D)// [B*L]    normalized pointer weights
#define WS_CTX (WS_PW + B * L)      // [B*D]    normalized context
#define WS_CW (WS_CTX + B * D)      // [B]      ctx·w_pgen[D:2D]

__device__ __forceinline__ float dot4(float4 a, float4 b) {
    return a.x * b.x + a.y * b.y + a.z * b.z + a.w * b.w;
}

// K1: blocks [0,512): per (b,ch) chunk of 32 enc rows — single pass:
//     e[row] = mask ? exp(enc·w + b_ptr) : 0; part[b,ch,:] += e[row]*enc[row,:]
//     blocks [512,2560): dec logits dl[r] = dec·(w1+w3) + b_pgen
__global__ __launch_bounds__(256) void k_fused1(const float* __restrict__ enc,
                                                const float* __restrict__ dec,
                                                const int* __restrict__ mask,
                                                const float* __restrict__ w_ptr,
                                                const float* __restrict__ b_ptr,
                                                const float* __restrict__ w_pgen,
                                                const float* __restrict__ b_pgen,
                                                float* __restrict__ ws) {
    __shared__ float lds[4 * D];
    int w = threadIdx.x >> 6;
    int l = threadIdx.x & 63;
    if (blockIdx.x < 512) {
        int b = blockIdx.x >> 6;
        int ch = blockIdx.x & 63;
        const float4* wp = (const float4*)(w_ptr + D);
        float4 u0 = wp[l], u1 = wp[l + 64], u2 = wp[l + 128], u3 = wp[l + 192];
        float bp = b_ptr[0];
        float4 a0 = make_float4(0, 0, 0, 0), a1 = a0, a2 = a0, a3 = a0;
#pragma unroll
        for (int jj = 0; jj < 8; ++jj) {
            int row = b * L + ch * 32 + w * 8 + jj;
            float e = 0.f;
            if (mask[row] != 0) {
                const float4* rp = (const float4*)(enc + (size_t)row * D);
                float4 v0 = rp[l], v1 = rp[l + 64], v2 = rp[l + 128],
                       v3 = rp[l + 192];
                float pd = dot4(v0, u0) + dot4(v1, u1) + dot4(v2, u2) +
                           dot4(v3, u3);
#pragma unroll
                for (int off = 32; off > 0; off >>= 1)
                    pd += __shfl_xor(pd, off, 64);
                e = expf(pd + bp);
                a0.x += e * v0.x; a0.y += e * v0.y; a0.z += e * v0.z; a0.w += e * v0.w;
                a1.x += e * v1.x; a1.y += e * v1.y; a1.z += e * v1.z; a1.w += e * v1.w;
                a2.x += e * v2.x; a2.y += e * v2.y; a2.z += e * v2.z; a2.w += e * v2.w;
                a3.x += e * v3.x; a3.y += e * v3.y; a3.z += e * v3.z; a3.w += e * v3.w;
            }
            if (l == 0) ws[WS_E + row] = e;
        }
        float4* lp = (float4*)lds + w * 256;
        lp[l] = a0; lp[l + 64] = a1; lp[l + 128] = a2; lp[l + 192] = a3;
        __syncthreads();
        int t = threadIdx.x;
        float4 s0 = ((float4*)lds)[t];
        float4 s1 = ((float4*)lds)[256 + t];
        float4 s2 = ((float4*)lds)[512 + t];
        float4 s3 = ((float4*)lds)[768 + t];
        float4 r;
        r.x = (s0.x + s1.x) + (s2.x + s3.x);
        r.y = (s0.y + s1.y) + (s2.y + s3.y);
        r.z = (s0.z + s1.z) + (s2.z + s3.z);
        r.w = (s0.w + s1.w) + (s2.w + s3.w);
        ((float4*)(ws + WS_PART))[(b * 64 + ch) * 256 + t] = r;
    } else {
        int r = (blockIdx.x - 512) * 4 + w;  // [0, B*S)
        const float4* row = (const float4*)(dec + (size_t)r * D);
        const float4* w1 = (const float4*)(w_pgen);
        const float4* w3 = (const float4*)(w_pgen + 2 * D);
        float acc = 0.f;
#pragma unroll
        for (int it = 0; it < 4; ++it) {
            int k = l + it * 64;
            float4 a = row[k];
            float4 u = w1[k];
            float4 t3 = w3[k];
            acc += a.x * (u.x + t3.x) + a.y * (u.y + t3.y) +
                   a.z * (u.z + t3.z) + a.w * (u.w + t3.w);
        }
#pragma unroll
        for (int off = 32; off > 0; off >>= 1) acc += __shfl_down(acc, off, 64);
        if (l == 0) ws[WS_DL + r] = acc + b_pgen[0];
    }
}

// K2: per b: sum(e) -> inv; pw = e*inv; ctx = inv * sum_ch part; cw = ctx·w2
__global__ __launch_bounds__(256) void k_mid(const float* __restrict__ w_pgen,
                                             float* __restrict__ ws) {
    int b = blockIdx.x;
    int t = threadIdx.x;
    int wave = t >> 6, lane = t & 63;
    __shared__ float red[4];
    __shared__ float s_inv;
    float ev[8];
    float s = 0.f;
#pragma unroll
    for (int j = 0; j < 8; ++j) {
        ev[j] = ws[WS_E + b * L + t + j * 256];
        s += ev[j];
    }
#pragma unroll
    for (int off = 32; off > 0; off >>= 1) s += __shfl_xor(s, off, 64);
    if (lane == 0) red[wave] = s;
    __syncthreads();
    if (t == 0) s_inv = 1.0f / ((red[0] + red[1]) + (red[2] + red[3]));
    __syncthreads();
    float inv = s_inv;
#pragma unroll
    for (int j = 0; j < 8; ++j)
        ws[WS_PW + b * L + t + j * 256] = ev[j] * inv;
    float cacc = 0.f;
    for (int d = t; d < D; d += 256) {
        float a = 0.f;
#pragma unroll 8
        for (int ch = 0; ch < 64; ++ch) a += ws[WS_PART + (b * 64 + ch) * D + d];
        float cv = a * inv;
        ws[WS_CTX + b * D + d] = cv;
        cacc += cv * w_pgen[D + d];
    }
#pragma unroll
    for (int off = 32; off > 0; off >>= 1) cacc += __shfl_down(cacc, off, 64);
    __syncthreads();
    if (lane == 0) red[wave] = cacc;
    __syncthreads();
    if (t == 0) ws[WS_CW + b] = (red[0] + red[1]) + (red[2] + red[3]);
}

// K3: one streaming sweep writing all three outputs.
__global__ __launch_bounds__(256) void k_out(const float* __restrict__ ws,
                                             float* __restrict__ out) {
    const long long N0 = (long long)B * S * (L / 4);  // 4194304
    const long long N1 = (B * S) / 4;                 // 2048
    const long long N2 = (long long)B * S * (D / 4);  // 2097152
    const float4* pw4 = (const float4*)(ws + WS_PW);
    const float4* ctx4 = (const float4*)(ws + WS_CTX);
    const float4* dl4 = (const float4*)(ws + WS_DL);
    const float* cw = ws + WS_CW;
    float4* out0 = (float4*)out;
    float4* out1 = (float4*)(out + (size_t)B * S * L);
    float4* out2 = (float4*)(out + (size_t)B * S * L + B * S);
    const long long total = N0 + N1 + N2;
    const long long stride = (long long)gridDim.x * 256;
    for (long long i = (long long)blockIdx.x * 256 + threadIdx.x; i < total;
         i += stride) {
        if (i < N0) {
            int l4 = (int)(i & 511);  // L/4 = 512
            int b = (int)(i >> 19);
            out0[i] = pw4[b * 512 + l4];
        } else if (i < N0 + N1) {
            int j = (int)(i - N0);
            float4 dl = dl4[j];
            float c = cw[j >> 8];
            float4 o;
            o.x = 1.0f / (1.0f + expf(-(dl.x + c)));
            o.y = 1.0f / (1.0f + expf(-(dl.y + c)));
            o.z = 1.0f / (1.0f + expf(-(dl.z + c)));
            o.w = 1.0f / (1.0f + expf(-(dl.w + c)));
            out1[j] = o;
        } else {
            long long j = i - N0 - N1;
            int d4 = (int)(j & 255);  // D/4 = 256
            int b = (int)(j >> 18);
            out2[j] = ctx4[b * 256 + d4];
        }
    }
}

extern "C" void kernel_launch(void* const* d_in, const int* in_sizes, int n_in,
                              void* d_out, int out_size, void* d_ws, size_t ws_size,
                              hipStream_t stream) {
    const float* dec = (const float*)d_in[0];
    const float* enc = (const float*)d_in[1];
    const int* mask = (const int*)d_in[2];
    const float* w_ptr = (const float*)d_in[4];
    const float* b_ptr = (const float*)d_in[5];
    const float* w_pgen = (const float*)d_in[6];
    const float* b_pgen = (const float*)d_in[7];
    float* out = (float*)d_out;
    float* ws = (float*)d_ws;

    k_fused1<<<2560, 256, 0, stream>>>(enc, dec, mask, w_ptr, b_ptr, w_pgen,
                                       b_pgen, ws);
    k_mid<<<B, 256, 0, stream>>>(w_pgen, ws);
    k_out<<<2048, 256, 0, stream>>>(ws, out);
}

// Round 4
// 40.059 us; speedup vs baseline: 1.4936x; 1.2614x over previous
//
#include <hip/hip_runtime.h>
#include <math.h>

#define B 8
#define S 1024
#define L 2048
#define D 1024

// ---- workspace layout (floats) ----
#define WS_E 0                   // [B*L]    unnormalized exp scores (0 if masked)
#define WS_DL (B * L)            // [B*S]    dec·(w1+w3) + b_pgen
#define WS_PART (WS_DL + B * S)  // [B*64*D] partial unnormalized ctx

__device__ __forceinline__ float dot4(float4 a, float4 b) {
    return a.x * b.x + a.y * b.y + a.z * b.z + a.w * b.w;
}

// K1: blocks [0,512): per (b,ch) chunk of 32 enc rows — single pass:
//     e[row] = mask ? exp(enc·w + b_ptr) : 0; part[b,ch,:] += e[row]*enc[row,:]
//     blocks [512,2560): dec logits dl[r] = dec·(w1+w3) + b_pgen
__global__ __launch_bounds__(256) void k_fused1(const float* __restrict__ enc,
                                                const float* __restrict__ dec,
                                                const int* __restrict__ mask,
                                                const float* __restrict__ w_ptr,
                                                const float* __restrict__ b_ptr,
                                                const float* __restrict__ w_pgen,
                                                const float* __restrict__ b_pgen,
                                                float* __restrict__ ws) {
    __shared__ float lds[4 * D];
    int w = threadIdx.x >> 6;
    int l = threadIdx.x & 63;
    if (blockIdx.x < 512) {
        int b = blockIdx.x >> 6;
        int ch = blockIdx.x & 63;
        const float4* wp = (const float4*)(w_ptr + D);
        float4 u0 = wp[l], u1 = wp[l + 64], u2 = wp[l + 128], u3 = wp[l + 192];
        float bp = b_ptr[0];
        float4 a0 = make_float4(0, 0, 0, 0), a1 = a0, a2 = a0, a3 = a0;
#pragma unroll
        for (int jj = 0; jj < 8; ++jj) {
            int row = b * L + ch * 32 + w * 8 + jj;
            float e = 0.f;
            if (mask[row] != 0) {
                const float4* rp = (const float4*)(enc + (size_t)row * D);
                float4 v0 = rp[l], v1 = rp[l + 64], v2 = rp[l + 128],
                       v3 = rp[l + 192];
                float pd = dot4(v0, u0) + dot4(v1, u1) + dot4(v2, u2) +
                           dot4(v3, u3);
#pragma unroll
                for (int off = 32; off > 0; off >>= 1)
                    pd += __shfl_xor(pd, off, 64);
                e = expf(pd + bp);
                a0.x += e * v0.x; a0.y += e * v0.y; a0.z += e * v0.z; a0.w += e * v0.w;
                a1.x += e * v1.x; a1.y += e * v1.y; a1.z += e * v1.z; a1.w += e * v1.w;
                a2.x += e * v2.x; a2.y += e * v2.y; a2.z += e * v2.z; a2.w += e * v2.w;
                a3.x += e * v3.x; a3.y += e * v3.y; a3.z += e * v3.z; a3.w += e * v3.w;
            }
            if (l == 0) ws[WS_E + row] = e;
        }
        float4* lp = (float4*)lds + w * 256;
        lp[l] = a0; lp[l + 64] = a1; lp[l + 128] = a2; lp[l + 192] = a3;
        __syncthreads();
        int t = threadIdx.x;
        float4 s0 = ((float4*)lds)[t];
        float4 s1 = ((float4*)lds)[256 + t];
        float4 s2 = ((float4*)lds)[512 + t];
        float4 s3 = ((float4*)lds)[768 + t];
        float4 r;
        r.x = (s0.x + s1.x) + (s2.x + s3.x);
        r.y = (s0.y + s1.y) + (s2.y + s3.y);
        r.z = (s0.z + s1.z) + (s2.z + s3.z);
        r.w = (s0.w + s1.w) + (s2.w + s3.w);
        ((float4*)(ws + WS_PART))[(b * 64 + ch) * 256 + t] = r;
    } else {
        int r = (blockIdx.x - 512) * 4 + w;  // [0, B*S)
        const float4* row = (const float4*)(dec + (size_t)r * D);
        const float4* w1 = (const float4*)(w_pgen);
        const float4* w3 = (const float4*)(w_pgen + 2 * D);
        float acc = 0.f;
#pragma unroll
        for (int it = 0; it < 4; ++it) {
            int k = l + it * 64;
            float4 a = row[k];
            float4 u = w1[k];
            float4 t3 = w3[k];
            acc += a.x * (u.x + t3.x) + a.y * (u.y + t3.y) +
                   a.z * (u.z + t3.z) + a.w * (u.w + t3.w);
        }
#pragma unroll
        for (int off = 32; off > 0; off >>= 1) acc += __shfl_down(acc, off, 64);
        if (l == 0) ws[WS_DL + r] = acc + b_pgen[0];
    }
}

// K2: all outputs in one kernel; per-b normalizers recomputed per block from
// the small L2/L3-resident e/part tables.
//   blocks [0,8):      C — cw[b] + p_gen row (long-latency, launched first)
//   blocks [8,520):    B — out2 ctx broadcast, (b, d-slice 256, s-slice 64)
//   blocks [520,1544): A — out0 pw broadcast, (b, s-slice 8)
__global__ __launch_bounds__(256) void k_out(const float* __restrict__ ws,
                                             const float* __restrict__ w_pgen,
                                             float* __restrict__ out) {
    const float4* e4 = (const float4*)(ws + WS_E);
    const float4* part4 = (const float4*)(ws + WS_PART);
    const float4* dl4 = (const float4*)(ws + WS_DL);
    float4* out0 = (float4*)out;
    float4* out1 = (float4*)(out + (size_t)B * S * L);
    float4* out2 = (float4*)(out + (size_t)B * S * L + B * S);
    int t = threadIdx.x;
    int wave = t >> 6, lane = t & 63;
    __shared__ float red[4];
    __shared__ float4 lds4[512];

    if (blockIdx.x < 8) {
        // ---- C: p_gen for batch b ----
        int b = blockIdx.x;
        float4 v1 = e4[b * 512 + t], v2 = e4[b * 512 + 256 + t];
        float s = (v1.x + v1.y + v1.z + v1.w) + (v2.x + v2.y + v2.z + v2.w);
#pragma unroll
        for (int off = 32; off > 0; off >>= 1) s += __shfl_xor(s, off, 64);
        if (lane == 0) red[wave] = s;
        __syncthreads();
        float inv = 1.0f / ((red[0] + red[1]) + (red[2] + red[3]));
        float4 c = make_float4(0, 0, 0, 0);
#pragma unroll 8
        for (int ch = 0; ch < 64; ++ch) {
            float4 p = part4[(b * 64 + ch) * 256 + t];
            c.x += p.x; c.y += p.y; c.z += p.z; c.w += p.w;
        }
        float4 w2 = ((const float4*)(w_pgen + D))[t];
        float cacc = dot4(c, w2);
#pragma unroll
        for (int off = 32; off > 0; off >>= 1) cacc += __shfl_xor(cacc, off, 64);
        __syncthreads();
        if (lane == 0) red[wave] = cacc;
        __syncthreads();
        float cw = inv * ((red[0] + red[1]) + (red[2] + red[3]));
        float4 dl = dl4[b * 256 + t];
        float4 o;
        o.x = 1.0f / (1.0f + expf(-(dl.x + cw)));
        o.y = 1.0f / (1.0f + expf(-(dl.y + cw)));
        o.z = 1.0f / (1.0f + expf(-(dl.z + cw)));
        o.w = 1.0f / (1.0f + expf(-(dl.w + cw)));
        out1[b * 256 + t] = o;
    } else if (blockIdx.x < 520) {
        // ---- B: out2 for (b, ds, ss) ----
        int bb = blockIdx.x - 8;
        int b = bb >> 6;
        int ds = bb & 3;
        int ss = (bb >> 2) & 15;
        float4 v1 = e4[b * 512 + t], v2 = e4[b * 512 + 256 + t];
        float s = (v1.x + v1.y + v1.z + v1.w) + (v2.x + v2.y + v2.z + v2.w);
#pragma unroll
        for (int off = 32; off > 0; off >>= 1) s += __shfl_xor(s, off, 64);
        if (lane == 0) red[wave] = s;
        __syncthreads();
        float inv = 1.0f / ((red[0] + red[1]) + (red[2] + red[3]));
        int d4 = t & 63;
        int chg = t >> 6;
        float4 c = make_float4(0, 0, 0, 0);
#pragma unroll
        for (int k = 0; k < 16; ++k) {
            int ch = chg + k * 4;
            float4 p = part4[(b * 64 + ch) * 256 + ds * 64 + d4];
            c.x += p.x; c.y += p.y; c.z += p.z; c.w += p.w;
        }
        lds4[chg * 64 + d4] = c;
        __syncthreads();
        if (t < 64) {
            float4 a0 = lds4[t], a1 = lds4[64 + t], a2 = lds4[128 + t],
                   a3 = lds4[192 + t];
            float4 cx;
            cx.x = ((a0.x + a1.x) + (a2.x + a3.x)) * inv;
            cx.y = ((a0.y + a1.y) + (a2.y + a3.y)) * inv;
            cx.z = ((a0.z + a1.z) + (a2.z + a3.z)) * inv;
            cx.w = ((a0.w + a1.w) + (a2.w + a3.w)) * inv;
            lds4[256 + t] = cx;
        }
        __syncthreads();
#pragma unroll
        for (int it = 0; it < 16; ++it) {
            int flat = it * 256 + t;
            int s_loc = flat >> 6;
            int dloc = flat & 63;
            out2[((size_t)(b * S + ss * 64 + s_loc)) * 256 + ds * 64 + dloc] =
                lds4[256 + dloc];
        }
    } else {
        // ---- A: out0 for (b, s-slice of 8) ----
        int ab = blockIdx.x - 520;
        int b = ab >> 7;
        int a = ab & 127;
        float4 v1 = e4[b * 512 + t], v2 = e4[b * 512 + 256 + t];
        lds4[t] = v1;
        lds4[256 + t] = v2;
        float s = (v1.x + v1.y + v1.z + v1.w) + (v2.x + v2.y + v2.z + v2.w);
#pragma unroll
        for (int off = 32; off > 0; off >>= 1) s += __shfl_xor(s, off, 64);
        if (lane == 0) red[wave] = s;
        __syncthreads();
        float inv = 1.0f / ((red[0] + red[1]) + (red[2] + red[3]));
#pragma unroll
        for (int it = 0; it < 16; ++it) {
            int flat = it * 256 + t;
            int s_loc = flat >> 9;
            int l4 = flat & 511;
            float4 e = lds4[l4];
            float4 o;
            o.x = e.x * inv; o.y = e.y * inv; o.z = e.z * inv; o.w = e.w * inv;
            out0[((size_t)(b * S + a * 8 + s_loc)) * 512 + l4] = o;
        }
    }
}

extern "C" void kernel_launch(void* const* d_in, const int* in_sizes, int n_in,
                              void* d_out, int out_size, void* d_ws, size_t ws_size,
                              hipStream_t stream) {
    const float* dec = (const float*)d_in[0];
    const float* enc = (const float*)d_in[1];
    const int* mask = (const int*)d_in[2];
    const float* w_ptr = (const float*)d_in[4];
    const float* b_ptr = (const float*)d_in[5];
    const float* w_pgen = (const float*)d_in[6];
    const float* b_pgen = (const float*)d_in[7];
    float* out = (float*)d_out;
    float* ws = (float*)d_ws;

    k_fused1<<<2560, 256, 0, stream>>>(enc, dec, mask, w_ptr, b_ptr, w_pgen,
                                       b_pgen, ws);
    k_out<<<1544, 256, 0, stream>>>(ws, w_pgen, out);
}